// Round 3
// baseline (2691.597 us; speedup 1.0000x reference)
//
#include <hip/hip_runtime.h>
#include <stdint.h>

#define B_   128
#define T_   128
#define C_   256
#define H_   4
#define HS_  64
#define L_   6
#define DFF_ 1024
#define V_   10000
#define M_   (B_ * T_)   // 16384

typedef unsigned short ushort_t;
typedef float  f32x4  __attribute__((ext_vector_type(4)));
typedef __bf16 bf16x8 __attribute__((ext_vector_type(8)));

__device__ __forceinline__ float bf2f(ushort_t u) {
    union { uint32_t i; float f; } v; v.i = ((uint32_t)u) << 16; return v.f;
}
__device__ __forceinline__ ushort_t f2bf(float f) {
    union { float f; uint32_t i; } v; v.f = f;
    uint32_t r = v.i + 0x7fff + ((v.i >> 16) & 1);
    return (ushort_t)(r >> 16);
}
__device__ __forceinline__ void unpack8(uint4 r, float* d) {
    d[0] = bf2f((ushort_t)(r.x & 0xffff)); d[1] = bf2f((ushort_t)(r.x >> 16));
    d[2] = bf2f((ushort_t)(r.y & 0xffff)); d[3] = bf2f((ushort_t)(r.y >> 16));
    d[4] = bf2f((ushort_t)(r.z & 0xffff)); d[5] = bf2f((ushort_t)(r.z >> 16));
    d[6] = bf2f((ushort_t)(r.w & 0xffff)); d[7] = bf2f((ushort_t)(r.w >> 16));
}

// ---------------------------------------------------------------------------
// fp32 -> bf16 elementwise convert (weights), 4 elems/thread
// ---------------------------------------------------------------------------
__global__ __launch_bounds__(256) void cvt_kernel(
    const float* __restrict__ src, ushort_t* __restrict__ dst, int n4)
{
    int i = blockIdx.x * 256 + threadIdx.x;
    if (i >= n4) return;
    float4 v = ((const float4*)src)[i];
    uint2 o;
    o.x = (uint32_t)f2bf(v.x) | ((uint32_t)f2bf(v.y) << 16);
    o.y = (uint32_t)f2bf(v.z) | ((uint32_t)f2bf(v.w) << 16);
    ((uint2*)dst)[i] = o;
}

// ---------------------------------------------------------------------------
// Embedding: x[b,t,:] = tok_emb[idx[b,t],:] + pos_emb[t,:]   (fp32 in/out)
// ---------------------------------------------------------------------------
__global__ __launch_bounds__(64) void embed_kernel(
    const int* __restrict__ idx, const float* __restrict__ tok,
    const float* __restrict__ pos, float* __restrict__ x)
{
    int row = blockIdx.x;           // 0..M_-1
    int t   = row & (T_ - 1);
    int tk  = idx[row];
    int c   = threadIdx.x * 4;
    float4 a = *(const float4*)(tok + (size_t)tk * C_ + c);
    float4 p = *(const float4*)(pos + (size_t)t  * C_ + c);
    float4 o = { a.x + p.x, a.y + p.y, a.z + p.z, a.w + p.w };
    *(float4*)(x + (size_t)row * C_ + c) = o;
}

// ---------------------------------------------------------------------------
// LayerNorm: h = (x - mean)/sqrt(var+eps)*g + b ; fp32 in, bf16 out
// one wave (64 threads) per row of 256
// ---------------------------------------------------------------------------
__global__ __launch_bounds__(64) void ln_kernel(
    const float* __restrict__ x, const float* __restrict__ g,
    const float* __restrict__ b, ushort_t* __restrict__ out)
{
    int row = blockIdx.x;
    int c   = threadIdx.x * 4;
    const float* xr = x + (size_t)row * C_;
    float4 v = *(const float4*)(xr + c);
    float s  = v.x + v.y + v.z + v.w;
    float sq = v.x * v.x + v.y * v.y + v.z * v.z + v.w * v.w;
    #pragma unroll
    for (int m = 1; m < 64; m <<= 1) {
        s  += __shfl_xor(s,  m);
        sq += __shfl_xor(sq, m);
    }
    float mean = s * (1.f / C_);
    float var  = sq * (1.f / C_) - mean * mean;
    float rstd = rsqrtf(var + 1e-5f);
    float4 gg = *(const float4*)(g + c);
    float4 bb = *(const float4*)(b + c);
    float o0 = (v.x - mean) * rstd * gg.x + bb.x;
    float o1 = (v.y - mean) * rstd * gg.y + bb.y;
    float o2 = (v.z - mean) * rstd * gg.z + bb.z;
    float o3 = (v.w - mean) * rstd * gg.w + bb.w;
    uint2 pk;
    pk.x = (uint32_t)f2bf(o0) | ((uint32_t)f2bf(o1) << 16);
    pk.y = (uint32_t)f2bf(o2) | ((uint32_t)f2bf(o3) << 16);
    *(uint2*)(out + (size_t)row * C_ + c) = pk;
}

// ---------------------------------------------------------------------------
// GEMM: out = act(A[M,K](lda) * B[K,N](ldb) + bias)   (A,B bf16; acc fp32)
// B row-major [K,N]; transposed on the fly into LDS [n][k] (pad stride 40).
// 128x128 tile, BK=32, 4 waves, each wave 4x4 of mfma_f32_16x16x32_bf16.
// MODE: 0 = bf16 store to outb; 1 = fp32 accumulate into fptr (residual);
//       2 = fp32 store to fptr. BIAS: add fp32 bias[col]. RELU. NGUARD: col<N.
// ---------------------------------------------------------------------------
template <int BIAS, int RELU, int MODE, int NGUARD>
__global__ __launch_bounds__(256) void gemm_kernel(
    const ushort_t* __restrict__ A, int lda,
    const ushort_t* __restrict__ B, int ldb,
    const float* __restrict__ bias,
    float* __restrict__ fptr,
    ushort_t* __restrict__ outb, int ldc,
    int N, int K)
{
    __shared__ ushort_t sA[128 * 32];   // [m][k]
    __shared__ ushort_t sB[128 * 40];   // [n][k], padded stride 40
    const int tid  = threadIdx.x;
    const int wave = tid >> 6;
    const int lane = tid & 63;
    const int quad = lane >> 4;
    const int l16  = lane & 15;
    const int m0 = blockIdx.y * 128;
    const int n0 = blockIdx.x * 128;
    const int wm = (wave >> 1) * 64;
    const int wn = (wave & 1) * 64;

    f32x4 acc[4][4] = {};

    const int e0 = tid * 8;
    for (int k0 = 0; k0 < K; k0 += 32) {
        #pragma unroll
        for (int c = 0; c < 2; ++c) {
            int e = e0 + c * 2048;      // 0..4088, step 8
            // A tile: [128 m][32 k], contiguous
            int ra = e >> 5;            // m: 0..127
            int ca = e & 31;            // k: {0,8,16,24}
            uint4 va = *(const uint4*)(A + (size_t)(m0 + ra) * lda + k0 + ca);
            *(uint4*)(sA + ra * 32 + ca) = va;
            // B tile: [32 k][128 n] -> scatter to sB[n][k]
            int kb = e >> 7;            // k: 0..31
            int nb = e & 127;           // n: {0,8,...,120}
            int cb = n0 + nb;
            if (NGUARD) cb = min(cb, N - 8);   // N % 8 == 0
            uint4 vb = *(const uint4*)(B + (size_t)(k0 + kb) * ldb + cb);
            ushort_t tmp[8];
            *(uint4*)tmp = vb;
            #pragma unroll
            for (int i = 0; i < 8; ++i)
                sB[(nb + i) * 40 + kb] = tmp[i];
        }
        __syncthreads();
        bf16x8 af[4], bF[4];
        #pragma unroll
        for (int i = 0; i < 4; ++i) {
            af[i] = *(const bf16x8*)(sA + (wm + i * 16 + l16) * 32 + quad * 8);
            bF[i] = *(const bf16x8*)(sB + (wn + i * 16 + l16) * 40 + quad * 8);
        }
        #pragma unroll
        for (int mi = 0; mi < 4; ++mi)
            #pragma unroll
            for (int ni = 0; ni < 4; ++ni)
                acc[mi][ni] = __builtin_amdgcn_mfma_f32_16x16x32_bf16(
                    af[mi], bF[ni], acc[mi][ni], 0, 0, 0);
        __syncthreads();
    }

    #pragma unroll
    for (int mi = 0; mi < 4; ++mi) {
        #pragma unroll
        for (int ni = 0; ni < 4; ++ni) {
            int col = n0 + wn + ni * 16 + l16;
            if (NGUARD && col >= N) continue;
            float bv = 0.f;
            if (BIAS) bv = bias[col];
            #pragma unroll
            for (int r = 0; r < 4; ++r) {
                int row = m0 + wm + mi * 16 + quad * 4 + r;
                float v = acc[mi][ni][r] + bv;
                if (RELU) v = fmaxf(v, 0.f);
                if (MODE == 1) {
                    size_t o = (size_t)row * ldc + col;
                    fptr[o] = fptr[o] + v;
                } else if (MODE == 2) {
                    fptr[(size_t)row * ldc + col] = v;
                } else {
                    outb[(size_t)row * ldc + col] = f2bf(v);
                }
            }
        }
    }
}

// ---------------------------------------------------------------------------
// Attention: per (b,h) block; qkv packed bf16 [M, 768] = [q(256) k(256) v(256)]
// online softmax (init from j=0), scale = C^-0.5 = 1/16 (reference quirk),
// causal. Output written IN PLACE over the q slice (safe: all q reads precede
// the block barrier; other blocks touch disjoint regions).
// ---------------------------------------------------------------------------
__global__ __launch_bounds__(128) void attn_kernel(ushort_t* __restrict__ qkv)
{
    __shared__ float sK[T_][HS_];
    __shared__ float sV[T_][HS_];
    const int bh = blockIdx.x;
    const int b  = bh >> 2;
    const int h  = bh & 3;
    const int tid = threadIdx.x;          // query row t
    const size_t base = (size_t)b * T_ * 768;

    for (int e = tid * 8; e < T_ * HS_; e += 128 * 8) {
        int r = e >> 6, c = e & 63;
        size_t off = base + (size_t)r * 768 + h * 64 + c;
        uint4 kk = *(const uint4*)(qkv + off + 256);
        uint4 vv = *(const uint4*)(qkv + off + 512);
        unpack8(kk, &sK[r][c]);
        unpack8(vv, &sV[r][c]);
    }
    float q[64];
    {
        size_t off = base + (size_t)tid * 768 + h * 64;
        #pragma unroll
        for (int c8 = 0; c8 < 8; ++c8) {
            uint4 r = *(const uint4*)(qkv + off + c8 * 8);
            unpack8(r, &q[c8 * 8]);
        }
    }
    __syncthreads();

    // j = 0 init: m=s0, l=1, acc=v0
    float m, l;
    float acc[64];
    {
        const float4* k0 = (const float4*)&sK[0][0];
        float s = 0.f;
        #pragma unroll
        for (int d4 = 0; d4 < 16; ++d4) {
            float4 kk = k0[d4];
            s += q[d4*4+0] * kk.x + q[d4*4+1] * kk.y
               + q[d4*4+2] * kk.z + q[d4*4+3] * kk.w;
        }
        m = s * 0.0625f;
        l = 1.f;
        #pragma unroll
        for (int d = 0; d < 64; ++d) acc[d] = sV[0][d];
    }

    for (int j = 1; j <= tid; ++j) {
        const float4* kj = (const float4*)&sK[j][0];
        float s = 0.f;
        #pragma unroll
        for (int d4 = 0; d4 < 16; ++d4) {
            float4 kk = kj[d4];
            s += q[d4*4+0] * kk.x + q[d4*4+1] * kk.y
               + q[d4*4+2] * kk.z + q[d4*4+3] * kk.w;
        }
        s *= 0.0625f;   // C^-0.5 (reference scales by n_embd, not head_size)
        float mn   = fmaxf(m, s);
        float p    = expf(s - mn);
        float corr = expf(m - mn);
        l = l * corr + p;
        const float4* vj = (const float4*)&sV[j][0];
        #pragma unroll
        for (int d4 = 0; d4 < 16; ++d4) {
            float4 vv = vj[d4];
            acc[d4*4+0] = acc[d4*4+0] * corr + p * vv.x;
            acc[d4*4+1] = acc[d4*4+1] * corr + p * vv.y;
            acc[d4*4+2] = acc[d4*4+2] * corr + p * vv.z;
            acc[d4*4+3] = acc[d4*4+3] * corr + p * vv.w;
        }
        m = mn;
    }
    float inv = 1.f / l;
    size_t orow = base + (size_t)tid * 768 + h * 64;   // in-place over q
    #pragma unroll
    for (int c8 = 0; c8 < 8; ++c8) {
        uint4 o;
        o.x = (uint32_t)f2bf(acc[c8*8+0]*inv) | ((uint32_t)f2bf(acc[c8*8+1]*inv) << 16);
        o.y = (uint32_t)f2bf(acc[c8*8+2]*inv) | ((uint32_t)f2bf(acc[c8*8+3]*inv) << 16);
        o.z = (uint32_t)f2bf(acc[c8*8+4]*inv) | ((uint32_t)f2bf(acc[c8*8+5]*inv) << 16);
        o.w = (uint32_t)f2bf(acc[c8*8+6]*inv) | ((uint32_t)f2bf(acc[c8*8+7]*inv) << 16);
        *(uint4*)(qkv + orow + c8 * 8) = o;
    }
}

// ---------------------------------------------------------------------------
extern "C" void kernel_launch(void* const* d_in, const int* in_sizes, int n_in,
                              void* d_out, int out_size, void* d_ws, size_t ws_size,
                              hipStream_t stream)
{
    const int*   idx   = (const int*)d_in[0];
    const float* tok   = (const float*)d_in[1];
    const float* pos   = (const float*)d_in[2];
    const float* ln1_g = (const float*)d_in[3];
    const float* ln1_b = (const float*)d_in[4];
    const float* wq    = (const float*)d_in[5];
    const float* wk    = (const float*)d_in[6];
    const float* wv    = (const float*)d_in[7];
    const float* projw = (const float*)d_in[8];
    const float* projb = (const float*)d_in[9];
    const float* ln2_g = (const float*)d_in[10];
    const float* ln2_b = (const float*)d_in[11];
    const float* w1    = (const float*)d_in[12];
    const float* b1    = (const float*)d_in[13];
    const float* w2    = (const float*)d_in[14];
    const float* b2    = (const float*)d_in[15];
    const float* lnf_g = (const float*)d_in[16];
    const float* lnf_b = (const float*)d_in[17];
    const float* lm_w  = (const float*)d_in[18];
    const float* lm_b  = (const float*)d_in[19];
    float* out = (float*)d_out;   // fp32 logits [M, V] = 655 MB

    // d_out doubles as scratch; every scratch region is fully consumed before
    // the LM-head GEMM overwrites d_out. Only h and lm_w(bf16) are read DURING
    // the LM GEMM, so they live in d_ws (13.5 MB).
    char* ob = (char*)d_out;
    ushort_t* big  = (ushort_t*)ob;                       // [0, 32 MB): qkv [M,768] / ffn hidden [M,1024], bf16
    float*    x    = (float*)(ob + 33554432);             // [32, 48 MB): fp32 residual [M,C]
    ushort_t* wqB  = (ushort_t*)(ob + 50331648);          // bf16 weights (per-layer arrays, all L)
    ushort_t* wkB  = (ushort_t*)(ob + 51118080);
    ushort_t* wvB  = (ushort_t*)(ob + 51904512);
    ushort_t* prB  = (ushort_t*)(ob + 52690944);
    ushort_t* w1B  = (ushort_t*)(ob + 53477376);
    ushort_t* w2B  = (ushort_t*)(ob + 56623104);
    ushort_t* h    = (ushort_t*)d_ws;                     // 8 MB bf16 [M,C]
    ushort_t* lmB  = (ushort_t*)((char*)d_ws + 8388608);  // 5.12 MB bf16 [C,V]

    // weight conversions fp32 -> bf16
    cvt_kernel<<<(L_*C_*C_/4 + 255)/256,   256, 0, stream>>>(wq,    wqB, L_*C_*C_/4);
    cvt_kernel<<<(L_*C_*C_/4 + 255)/256,   256, 0, stream>>>(wk,    wkB, L_*C_*C_/4);
    cvt_kernel<<<(L_*C_*C_/4 + 255)/256,   256, 0, stream>>>(wv,    wvB, L_*C_*C_/4);
    cvt_kernel<<<(L_*C_*C_/4 + 255)/256,   256, 0, stream>>>(projw, prB, L_*C_*C_/4);
    cvt_kernel<<<(L_*C_*DFF_/4 + 255)/256, 256, 0, stream>>>(w1,    w1B, L_*C_*DFF_/4);
    cvt_kernel<<<(L_*C_*DFF_/4 + 255)/256, 256, 0, stream>>>(w2,    w2B, L_*C_*DFF_/4);
    cvt_kernel<<<(C_*V_/4 + 255)/256,      256, 0, stream>>>(lm_w,  lmB, C_*V_/4);

    embed_kernel<<<M_, 64, 0, stream>>>(idx, tok, pos, x);

    for (int l = 0; l < L_; ++l) {
        ln_kernel<<<M_, 64, 0, stream>>>(x, ln1_g + l * C_, ln1_b + l * C_, h);
        // q, k, v GEMMs into packed big [M, 768]
        gemm_kernel<0,0,0,0><<<dim3(2,128), 256, 0, stream>>>(
            h, C_, wqB + (size_t)l * C_ * C_, C_, nullptr, nullptr, big,       768, C_, C_);
        gemm_kernel<0,0,0,0><<<dim3(2,128), 256, 0, stream>>>(
            h, C_, wkB + (size_t)l * C_ * C_, C_, nullptr, nullptr, big + 256, 768, C_, C_);
        gemm_kernel<0,0,0,0><<<dim3(2,128), 256, 0, stream>>>(
            h, C_, wvB + (size_t)l * C_ * C_, C_, nullptr, nullptr, big + 512, 768, C_, C_);
        attn_kernel<<<B_ * H_, 128, 0, stream>>>(big);
        // proj: x += att @ proj_w + proj_b   (att = big cols [0,256), lda=768)
        gemm_kernel<1,0,1,0><<<dim3(2,128), 256, 0, stream>>>(
            big, 768, prB + (size_t)l * C_ * C_, C_, projb + l * C_, x, nullptr, C_, C_, C_);
        ln_kernel<<<M_, 64, 0, stream>>>(x, ln2_g + l * C_, ln2_b + l * C_, h);
        // ffn1: big = relu(h @ w1 + b1)   [M, 1024]
        gemm_kernel<1,1,0,0><<<dim3(8,128), 256, 0, stream>>>(
            h, C_, w1B + (size_t)l * C_ * DFF_, DFF_, b1 + l * DFF_, nullptr, big, DFF_, DFF_, C_);
        // ffn2: x += big @ w2 + b2
        gemm_kernel<1,0,1,0><<<dim3(2,128), 256, 0, stream>>>(
            big, DFF_, w2B + (size_t)l * DFF_ * C_, C_, b2 + l * C_, x, nullptr, C_, C_, DFF_);
    }
    ln_kernel<<<M_, 64, 0, stream>>>(x, lnf_g, lnf_b, h);
    // LM head: out(fp32) = h @ lm_w + lm_b
    gemm_kernel<1,0,2,1><<<dim3((V_ + 127) / 128, 128), 256, 0, stream>>>(
        h, C_, lmB, V_, lm_b, out, nullptr, V_, V_, C_);
}